// Round 2
// baseline (1290.280 us; speedup 1.0000x reference)
//
#include <hip/hip_runtime.h>
#include <hip/hip_bf16.h>

// Exact tanh via exp: tanh(x) = sign(x) * (1-e)/(1+e), e = exp(-2|x|)
__device__ __forceinline__ float fast_tanh(float x) {
    float e = __expf(-2.0f * fabsf(x));
    float r = __fdividef(1.0f - e, 1.0f + e);
    return copysignf(r, x);
}

__device__ __forceinline__ float leaky(float x) {
    return x > 0.0f ? x : 0.01f * x;
}

// ---------------- counting sort (by dst) ----------------

__global__ void hist_k(const int* __restrict__ dst, int* __restrict__ cnt,
                       int E) {
    int e = blockIdx.x * 256 + threadIdx.x;
    if (e < E) atomicAdd(&cnt[dst[e]], 1);
}

// block partial sums of cnt (512/block)
__global__ void scan_blocksum(const int* __restrict__ cnt,
                              int* __restrict__ bsum, int NS) {
    __shared__ int s[512];
    int i = blockIdx.x * 512 + threadIdx.x;
    s[threadIdx.x] = (i < NS) ? cnt[i] : 0;
    __syncthreads();
    for (int off = 256; off > 0; off >>= 1) {
        if (threadIdx.x < off) s[threadIdx.x] += s[threadIdx.x + off];
        __syncthreads();
    }
    if (threadIdx.x == 0) bsum[blockIdx.x] = s[0];
}

// exclusive scan of nb (<=128) block sums, single block of 128 threads
__global__ void scan_small(int* __restrict__ bsum, int n) {
    __shared__ int s[128];
    int t = threadIdx.x;
    int v = (t < n) ? bsum[t] : 0;
    s[t] = v;
    __syncthreads();
    for (int off = 1; off < 128; off <<= 1) {
        int x = (t >= off) ? s[t - off] : 0;
        __syncthreads();
        s[t] += x;
        __syncthreads();
    }
    if (t < n) bsum[t] = s[t] - v;  // exclusive
}

// per-element exclusive prefix = block offset + local exclusive scan
__global__ void scan_final(const int* __restrict__ cnt,
                           const int* __restrict__ bsum, int* __restrict__ rowp,
                           int NS) {
    __shared__ int s[512];
    int t = threadIdx.x;
    int i = blockIdx.x * 512 + t;
    int v = (i < NS) ? cnt[i] : 0;
    s[t] = v;
    __syncthreads();
    for (int off = 1; off < 512; off <<= 1) {
        int x = (t >= off) ? s[t - off] : 0;
        __syncthreads();
        s[t] += x;
        __syncthreads();
    }
    if (i < NS) rowp[i] = bsum[blockIdx.x] + s[t] - v;
}

// cursor starts as exclusive prefix; after this it's destroyed (that's fine,
// only perm is consumed downstream). Intra-bin order nondeterministic -> only
// ulp-level fp reassociation in the sums.
__global__ void scatter_k(const int* __restrict__ dst, int* __restrict__ cursor,
                          int* __restrict__ perm, int E) {
    int e = blockIdx.x * 256 + threadIdx.x;
    if (e < E) {
        int p = atomicAdd(&cursor[dst[e]], 1);
        perm[p] = e;
    }
}

// ---------------- edge MLP + run-aggregated scatter ----------------
// One thread per (dst-sorted) edge: gather -> [IN]x32 MLP -> leaky -> 32x64 ->
// tanh -> wave LDS transpose -> per-16-edge-run register aggregation ->
// coalesced atomic flush (one 64B line per distinct dst per chunk).
// IN = 5 + FEAT  (pos_src(2), pos_dst(2), dis(1), feat(FEAT))
template <int FEAT>
__global__ __launch_bounds__(256, 2) void edge_mlp_scatter(
    const float* __restrict__ pos_src_tbl,  // [*,2] indexed by src
    const float* __restrict__ pos_dst_tbl,  // [*,2] indexed by dst
    const float* __restrict__ dis,          // [E]
    const float* __restrict__ feat_tbl,     // [*,FEAT] indexed by src
    const int* __restrict__ src, const int* __restrict__ dst,
    const int* __restrict__ perm,  // dst-sorted edge ids
    const float* __restrict__ W1,  // [(5+FEAT), 32] row-major
    const float* __restrict__ b1,  // [32]
    const float* __restrict__ W2,  // [32, 64] row-major
    const float* __restrict__ b2,  // [64]
    float* __restrict__ accum,     // [N_S, 64]
    int E) {
    __shared__ float tr[4][16][65];  // [wave][chunk-channel][edge] (+pad)
    __shared__ int dstsh[4][64];     // dst row base per sorted edge (or -1)

    const int tid = threadIdx.x;
    const int lane = tid & 63;
    const int wave = tid >> 6;
    const int e = blockIdx.x * 256 + tid;
    const bool valid = e < E;
    const int ee = perm[valid ? e : (E - 1)];

    const int s = src[ee];
    const int d = dst[ee];

    float f[5];
    f[0] = pos_src_tbl[2 * s];
    f[1] = pos_src_tbl[2 * s + 1];
    f[2] = pos_dst_tbl[2 * d];
    f[3] = pos_dst_tbl[2 * d + 1];
    f[4] = dis[ee];

    // ---- layer 1: hid = leaky(inp @ W1 + b1) ----
    float hid[32];
#pragma unroll
    for (int j = 0; j < 32; j++) hid[j] = b1[j];
#pragma unroll
    for (int k = 0; k < 5; k++) {
        const float v = f[k];
        const float* w = W1 + k * 32;
#pragma unroll
        for (int j = 0; j < 32; j++) hid[j] += v * w[j];
    }
    const float4* fp = reinterpret_cast<const float4*>(feat_tbl + s * FEAT);
#pragma unroll
    for (int c = 0; c < FEAT / 4; c++) {
        const float4 v = fp[c];
        const float* w = W1 + (5 + 4 * c) * 32;
#pragma unroll
        for (int j = 0; j < 32; j++) {
            hid[j] += v.x * w[j];
            hid[j] += v.y * w[32 + j];
            hid[j] += v.z * w[64 + j];
            hid[j] += v.w * w[96 + j];
        }
    }
#pragma unroll
    for (int j = 0; j < 32; j++) hid[j] = leaky(hid[j]);

    // ---- layer 2: out = tanh(hid @ W2 + b2) ----
    float out[64];
#pragma unroll
    for (int j = 0; j < 64; j++) out[j] = b2[j];
#pragma unroll
    for (int k = 0; k < 32; k++) {
        const float v = hid[k];
        const float* w = W2 + k * 64;
#pragma unroll
        for (int j = 0; j < 64; j++) out[j] += v * w[j];
    }
#pragma unroll
    for (int j = 0; j < 64; j++) out[j] = fast_tanh(out[j]);

    // ---- scatter: transpose 16-ch chunks; run-aggregate sorted dsts ----
    dstsh[wave][lane] = valid ? (d * 64) : -1;
    const int ch = lane & 15;  // channel within chunk
    const int q = lane >> 4;   // 16-edge group
#pragma unroll 1
    for (int c = 0; c < 4; c++) {
#pragma unroll
        for (int jp = 0; jp < 16; jp++)
            tr[wave][jp][lane] = valid ? out[c * 16 + jp] : 0.0f;
        __syncthreads();
        // lanes (ch, q): serially reduce the q-th 16-edge group's channel ch;
        // dst runs are contiguous (sorted), flush once per run.
        float acc = 0.0f;
        int cur = dstsh[wave][q * 16];
#pragma unroll
        for (int i = 0; i < 16; i++) {
            const int e2 = q * 16 + i;
            const int d2 = dstsh[wave][e2];
            const float v = tr[wave][ch][e2];
            if (d2 != cur) {
                if (cur >= 0) unsafeAtomicAdd(accum + cur + c * 16 + ch, acc);
                cur = d2;
                acc = v;
            } else {
                acc += v;
            }
        }
        if (cur >= 0) unsafeAtomicAdd(accum + cur + c * 16 + ch, acc);
        __syncthreads();
    }
}

// One thread per node: inp = [pos(2), h(64), sum_u(64), sum_h(64)] (194)
// out = tanh(leaky(inp@W1+b1)@W2+b2).  NOTE: sum_h aliases outp (d_out reuse);
// safe because thread n reads only row n before writing row n.
__global__ __launch_bounds__(256, 2) void node_update(
    const float* __restrict__ pos_s, const float* __restrict__ h,
    const float* __restrict__ sum_u, const float* sum_h,
    const float* __restrict__ W1,  // [194,32]
    const float* __restrict__ b1, const float* __restrict__ W2,
    const float* __restrict__ b2, float* outp, int N) {
    const int n = blockIdx.x * 256 + threadIdx.x;
    if (n >= N) return;

    float hid[32];
#pragma unroll
    for (int j = 0; j < 32; j++) hid[j] = b1[j];

    {
        const float p0 = pos_s[2 * n], p1 = pos_s[2 * n + 1];
#pragma unroll
        for (int j = 0; j < 32; j++) hid[j] += p0 * W1[j] + p1 * W1[32 + j];
    }

    const float4* hp = reinterpret_cast<const float4*>(h + n * 64);
#pragma unroll
    for (int c = 0; c < 16; c++) {
        const float4 v = hp[c];
        const float* w = W1 + (2 + 4 * c) * 32;
#pragma unroll
        for (int j = 0; j < 32; j++) {
            hid[j] += v.x * w[j];
            hid[j] += v.y * w[32 + j];
            hid[j] += v.z * w[64 + j];
            hid[j] += v.w * w[96 + j];
        }
    }
    const float4* up = reinterpret_cast<const float4*>(sum_u + n * 64);
#pragma unroll
    for (int c = 0; c < 16; c++) {
        const float4 v = up[c];
        const float* w = W1 + (66 + 4 * c) * 32;
#pragma unroll
        for (int j = 0; j < 32; j++) {
            hid[j] += v.x * w[j];
            hid[j] += v.y * w[32 + j];
            hid[j] += v.z * w[64 + j];
            hid[j] += v.w * w[96 + j];
        }
    }
    const float4* sp = reinterpret_cast<const float4*>(sum_h + n * 64);
#pragma unroll
    for (int c = 0; c < 16; c++) {
        const float4 v = sp[c];
        const float* w = W1 + (130 + 4 * c) * 32;
#pragma unroll
        for (int j = 0; j < 32; j++) {
            hid[j] += v.x * w[j];
            hid[j] += v.y * w[32 + j];
            hid[j] += v.z * w[64 + j];
            hid[j] += v.w * w[96 + j];
        }
    }
#pragma unroll
    for (int j = 0; j < 32; j++) hid[j] = leaky(hid[j]);

    float out[64];
#pragma unroll
    for (int j = 0; j < 64; j++) out[j] = b2[j];
#pragma unroll
    for (int k = 0; k < 32; k++) {
        const float v = hid[k];
        const float* w = W2 + k * 64;
#pragma unroll
        for (int j = 0; j < 64; j++) out[j] += v * w[j];
    }

    float4* op = reinterpret_cast<float4*>(outp + n * 64);
#pragma unroll
    for (int c = 0; c < 16; c++) {
        float4 v;
        v.x = fast_tanh(out[4 * c + 0]);
        v.y = fast_tanh(out[4 * c + 1]);
        v.z = fast_tanh(out[4 * c + 2]);
        v.w = fast_tanh(out[4 * c + 3]);
        op[c] = v;
    }
}

extern "C" void kernel_launch(void* const* d_in, const int* in_sizes, int n_in,
                              void* d_out, int out_size, void* d_ws,
                              size_t ws_size, hipStream_t stream) {
    (void)n_in;
    (void)out_size;
    (void)ws_size;
    const float* h = (const float*)d_in[0];
    const float* u = (const float*)d_in[1];
    const float* pos_s = (const float*)d_in[2];
    const float* pos_a = (const float*)d_in[3];
    const float* dis_a2s = (const float*)d_in[4];
    const float* dis_s2s = (const float*)d_in[5];
    const int* a2s_src = (const int*)d_in[6];
    const int* a2s_dst = (const int*)d_in[7];
    const int* s2s_src = (const int*)d_in[8];
    const int* s2s_dst = (const int*)d_in[9];
    const float* a2s_W1 = (const float*)d_in[10];
    const float* a2s_b1 = (const float*)d_in[11];
    const float* a2s_W2 = (const float*)d_in[12];
    const float* a2s_b2 = (const float*)d_in[13];
    const float* s2s_W1 = (const float*)d_in[14];
    const float* s2s_b1 = (const float*)d_in[15];
    const float* s2s_W2 = (const float*)d_in[16];
    const float* s2s_b2 = (const float*)d_in[17];
    const float* upd_W1 = (const float*)d_in[18];
    const float* upd_b1 = (const float*)d_in[19];
    const float* upd_W2 = (const float*)d_in[20];
    const float* upd_b2 = (const float*)d_in[21];

    const int E = in_sizes[6];        // a2s_src count (== s2s count)
    const int NS = in_sizes[0] / 64;  // h rows

    // ws layout: sum_u[NS*64] f32 | cnt[NS] | rowp[NS] | perm[E] | bsum[128]
    // peak ~19.7 MB (round-1 proved >=12.8 MB exists)
    float* sum_u = (float*)d_ws;
    int* cnt = (int*)((char*)d_ws + (size_t)NS * 64 * sizeof(float));
    int* rowp = cnt + NS;
    int* perm = rowp + NS;
    int* bsum = perm + E;

    float* sum_h = (float*)d_out;  // accumulate s2s directly in d_out

    hipMemsetAsync(sum_u, 0, (size_t)NS * 64 * sizeof(float), stream);
    hipMemsetAsync(sum_h, 0, (size_t)NS * 64 * sizeof(float), stream);

    const int eblocks = (E + 255) / 256;
    const int nb = (NS + 511) / 512;  // <=128 for NS<=65536

    // ---- a2s: sort by dst, then MLP+aggregated scatter ----
    hipMemsetAsync(cnt, 0, (size_t)NS * sizeof(int), stream);
    hist_k<<<eblocks, 256, 0, stream>>>(a2s_dst, cnt, E);
    scan_blocksum<<<nb, 512, 0, stream>>>(cnt, bsum, NS);
    scan_small<<<1, 128, 0, stream>>>(bsum, nb);
    scan_final<<<nb, 512, 0, stream>>>(cnt, bsum, rowp, NS);
    scatter_k<<<eblocks, 256, 0, stream>>>(a2s_dst, rowp, perm, E);
    edge_mlp_scatter<16><<<eblocks, 256, 0, stream>>>(
        pos_a, pos_s, dis_a2s, u, a2s_src, a2s_dst, perm, a2s_W1, a2s_b1,
        a2s_W2, a2s_b2, sum_u, E);

    // ---- s2s: same pipeline, reusing cnt/rowp/perm ----
    hipMemsetAsync(cnt, 0, (size_t)NS * sizeof(int), stream);
    hist_k<<<eblocks, 256, 0, stream>>>(s2s_dst, cnt, E);
    scan_blocksum<<<nb, 512, 0, stream>>>(cnt, bsum, NS);
    scan_small<<<1, 128, 0, stream>>>(bsum, nb);
    scan_final<<<nb, 512, 0, stream>>>(cnt, bsum, rowp, NS);
    scatter_k<<<eblocks, 256, 0, stream>>>(s2s_dst, rowp, perm, E);
    edge_mlp_scatter<64><<<eblocks, 256, 0, stream>>>(
        pos_s, pos_s, dis_s2s, h, s2s_src, s2s_dst, perm, s2s_W1, s2s_b1,
        s2s_W2, s2s_b2, sum_h, E);

    // ---- node update ----
    const int nblocks = (NS + 255) / 256;
    node_update<<<nblocks, 256, 0, stream>>>(pos_s, h, sum_u, sum_h, upd_W1,
                                             upd_b1, upd_W2, upd_b2,
                                             (float*)d_out, NS);
}